// Round 16
// baseline (212.745 us; speedup 1.0000x reference)
//
#include <hip/hip_runtime.h>
#include <hip/hip_fp16.h>
#include <math.h>

#define NEG_SLOPE 0.2f

__device__ __forceinline__ float sigm(float x) { return 1.0f / (1.0f + __expf(-x)); }
__device__ __forceinline__ float tanh_fast(float x) {
    float xc = fminf(fmaxf(x, -15.0f), 15.0f);
    float e2 = __expf(2.0f * xc);
    return (e2 - 1.0f) / (e2 + 1.0f);
}
__device__ __forceinline__ float lrelu(float x) { return (x > 0.0f) ? x : NEG_SLOPE * x; }

typedef _Float16 h2v __attribute__((ext_vector_type(2)));
__device__ __forceinline__ float fdot2h(h2v a, h2v b, float c) {
#if __has_builtin(__builtin_amdgcn_fdot2)
    return __builtin_amdgcn_fdot2(a, b, c, false);
#else
    return (float)a[0] * (float)b[0] + (float)a[1] * (float)b[1] + c;
#endif
}

// dot over 8 fp16 dims held as uint4 (4 x v_dot2)
__device__ __forceinline__ float dot16(const uint4& w, const uint4& h, float acc) {
    const h2v* wp = reinterpret_cast<const h2v*>(&w);
    const h2v* hp = reinterpret_cast<const h2v*>(&h);
    acc = fdot2h(wp[0], hp[0], acc);
    acc = fdot2h(wp[1], hp[1], acc);
    acc = fdot2h(wp[2], hp[2], acc);
    acc = fdot2h(wp[3], hp[3], acc);
    return acc;
}

// AGPR spill/fill: weights parked in the accumulator file, outside the VGPR
// allocator's pressure model (which evicted them to L2 in R12-R15).
#define AGW4(d0, d1, d2, d3, src) \
    asm volatile("v_accvgpr_write_b32 %0, %4\n\t" \
                 "v_accvgpr_write_b32 %1, %5\n\t" \
                 "v_accvgpr_write_b32 %2, %6\n\t" \
                 "v_accvgpr_write_b32 %3, %7" \
                 : "=a"(d0), "=a"(d1), "=a"(d2), "=a"(d3) \
                 : "v"((src).x), "v"((src).y), "v"((src).z), "v"((src).w))

#define AGR4(dst, s0, s1, s2, s3) \
    asm volatile("v_accvgpr_read_b32 %0, %4\n\t" \
                 "v_accvgpr_read_b32 %1, %5\n\t" \
                 "v_accvgpr_read_b32 %2, %6\n\t" \
                 "v_accvgpr_read_b32 %3, %7" \
                 : "=v"((dst).x), "=v"((dst).y), "=v"((dst).z), "=v"((dst).w) \
                 : "a"(s0), "a"(s1), "a"(s2), "a"(s3))

// ---------------- K1: histogram of dst ----------------
__global__ void k_hist(const int* __restrict__ dst, int* __restrict__ deg, int E) {
    int e = blockIdx.x * 256 + threadIdx.x;
    if (e < E) atomicAdd(deg + dst[e], 1);
}

// ---------------- scan (3 kernels, multi-block) ----------------
__global__ __launch_bounds__(256) void k_scan1(const int* __restrict__ deg,
                                               int* __restrict__ blksum, int N) {
    __shared__ int s[256];
    int tid = threadIdx.x;
    int i = blockIdx.x * 256 + tid;
    int v = (i < N) ? deg[i] : 0;
    s[tid] = v;
    __syncthreads();
    #pragma unroll
    for (int off = 128; off > 0; off >>= 1) {
        if (tid < off) s[tid] += s[tid + off];
        __syncthreads();
    }
    if (tid == 0) blksum[blockIdx.x] = s[0];
}

__global__ __launch_bounds__(256) void k_scan2(const int* __restrict__ blksum,
                                               int* __restrict__ blkoff, int nb) {
    __shared__ int s[256];
    int tid = threadIdx.x;
    int v = (tid < nb) ? blksum[tid] : 0;
    s[tid] = v;
    __syncthreads();
    for (int off = 1; off < 256; off <<= 1) {
        int t = (tid >= off) ? s[tid - off] : 0;
        __syncthreads();
        s[tid] += t;
        __syncthreads();
    }
    if (tid < nb) blkoff[tid] = s[tid] - v;   // exclusive
}

__global__ __launch_bounds__(256) void k_scan3(const int* __restrict__ deg,
                                               const int* __restrict__ blkoff,
                                               int* __restrict__ rowptr,
                                               int* __restrict__ cursor, int N, int E) {
    __shared__ int s[256];
    int tid = threadIdx.x;
    int i = blockIdx.x * 256 + tid;
    int v = (i < N) ? deg[i] : 0;
    s[tid] = v;
    __syncthreads();
    for (int off = 1; off < 256; off <<= 1) {
        int t = (tid >= off) ? s[tid - off] : 0;
        __syncthreads();
        s[tid] += t;
        __syncthreads();
    }
    int excl = s[tid] - v + blkoff[blockIdx.x];
    if (i < N) { rowptr[i] = excl; cursor[i] = excl; }
    if (i == N - 1) rowptr[N] = E;
}

// ---------------- K3: scatter edges into CSR (by dst) ----------------
__global__ void k_scatter(const int* __restrict__ src, const int* __restrict__ dst,
                          int* __restrict__ cursor, int* __restrict__ csr_src, int E) {
    int e = blockIdx.x * 256 + threadIdx.x;
    if (e < E) {
        int pos = atomicAdd(cursor + dst[e], 1);
        csr_src[pos] = src[e];
    }
}

// ---------------- K_PREP: fused {k_wt | k_pack2 | k_pre | k_zero} by block range ----------------
__global__ __launch_bounds__(256) void k_prep(
    const float* __restrict__ W_ih1, float* __restrict__ Wt, int n_node,
    const float* __restrict__ W_hh2, const float* __restrict__ W_ih2,
    const float* __restrict__ W_hh1,
    uint4* __restrict__ wc2p, uint4* __restrict__ wi2p, uint4* __restrict__ w1p,
    const float* __restrict__ W_gat, const float* __restrict__ a_src,
    const float* __restrict__ a_dst, float* __restrict__ wa,
    int* __restrict__ deg, int N) {
    int blk = blockIdx.x, tid = threadIdx.x;
    if (blk < 128) {
        __shared__ float tle[32][33];
        int kt = blk & 31;
        int gt = blk >> 5;
        for (int i = tid; i < 1024; i += 256) {
            int gl = i >> 5, kl = i & 31;
            int g = gt * 32 + gl, k = kt * 32 + kl;
            tle[gl][kl] = (k < n_node) ? W_ih1[(size_t)g * n_node + k] : 0.0f;
        }
        __syncthreads();
        for (int i = tid; i < 1024; i += 256) {
            int kl = i >> 5, gl = i & 31;
            int k = kt * 32 + kl, g = gt * 32 + gl;
            if (k < n_node) Wt[(size_t)k * 128 + g] = tle[gl][kl];
        }
    } else if (blk < 170) {
        int i = (blk - 128) * 256 + tid;   // 0..10751
        __align__(16) _Float16 tmp[8];
        if (i < 8192) {
            int jj = i >> 8, t = i & 255;
            int p = jj >> 4, j = jj & 15;
            int r = (t & 1) * 256 + p * 128 + (t >> 1);
            const float* s = W_hh2 + (size_t)r * 128 + j * 8;
            #pragma unroll
            for (int k = 0; k < 8; ++k) tmp[k] = (_Float16)s[k];
            wc2p[jj * 256 + t] = *(const uint4*)tmp;
        } else if (i < 10240) {
            int ii = i - 8192;
            int jj = ii >> 8, t = ii & 255;
            int p = jj >> 2, j = jj & 3;
            int r = (t & 1) * 256 + p * 128 + (t >> 1);
            const float* s = W_ih2 + (size_t)r * 32 + j * 8;
            #pragma unroll
            for (int k = 0; k < 8; ++k) tmp[k] = (_Float16)s[k];
            wi2p[jj * 256 + t] = *(const uint4*)tmp;
        } else if (i < 10752) {
            int ii = i - 10240;
            int jj = ii >> 6, l = ii & 63;
            int p = jj >> 2, j = jj & 3;
            int r = p * 64 + l;
            const float* s = W_hh1 + (size_t)r * 32 + j * 8;
            #pragma unroll
            for (int k = 0; k < 8; ++k) tmp[k] = (_Float16)s[k];
            w1p[jj * 64 + l] = *(const uint4*)tmp;
        }
    } else if (blk == 170) {
        int k = tid >> 3, h = tid & 7;
        float s1 = 0.0f, s2 = 0.0f;
        for (int c = 0; c < 32; ++c) {
            float wv = W_gat[k * 256 + h * 32 + c];
            s1 += wv * a_src[h * 32 + c];
            s2 += wv * a_dst[h * 32 + c];
        }
        wa[tid] = s1;
        wa[256 + tid] = s2;
    } else {
        int i = (blk - 171) * 256 + tid;
        if (i < N) deg[i] = 0;
    }
}

// ---------------- K4b: asrc/adst = x @ wa ----------------
__global__ __launch_bounds__(256) void k_att(const float* __restrict__ x,
                                             const float* __restrict__ wa,
                                             float* __restrict__ asrc,
                                             float* __restrict__ adst) {
    __shared__ float xs[32 * 33];
    __shared__ float was[256], wad[256];
    int tid = threadIdx.x;
    int n0 = blockIdx.x * 32;
    for (int i = tid; i < 1024; i += 256) {
        int nl = i >> 5, k = i & 31;
        xs[nl * 33 + k] = x[(size_t)(n0 + nl) * 32 + k];
    }
    was[tid] = wa[tid];
    wad[tid] = wa[256 + tid];
    __syncthreads();
    int nl = tid >> 3, h = tid & 7;
    float s1 = 0.0f, s2 = 0.0f;
    #pragma unroll
    for (int k = 0; k < 32; ++k) {
        float xv = xs[nl * 33 + k];
        s1 += xv * was[k * 8 + h];
        s2 += xv * wad[k * 8 + h];
    }
    asrc[(size_t)(n0 + nl) * 8 + h] = s1;
    adst[(size_t)(n0 + nl) * 8 + h] = s2;
}

// ---------------- K5: GAT gather, 8-deep MLP chunks ----------------
__global__ __launch_bounds__(256) void k_gat(
    const int* __restrict__ rowptr, const int* __restrict__ csr_src,
    const float* __restrict__ asrc, const float* __restrict__ adst,
    const float* __restrict__ x, float* __restrict__ z, int N) {
    int w = (blockIdx.x * 256 + threadIdx.x) >> 6;
    int lane = threadIdx.x & 63;
    if (w >= N) return;
    int r0 = rowptr[w], r1 = rowptr[w + 1];
    int h = lane >> 3, kq = lane & 7;
    float ad = adst[w * 8 + h];
    float4 acc = make_float4(0.0f, 0.0f, 0.0f, 0.0f);
    float den = 0.0f;
    const float4* x4 = (const float4*)x;
    for (int i = r0; i < r1; i += 8) {
        int rem = r1 - i;
        int s0 = csr_src[i];
        int s1 = (rem > 1) ? csr_src[i + 1] : s0;
        int s2 = (rem > 2) ? csr_src[i + 2] : s0;
        int s3 = (rem > 3) ? csr_src[i + 3] : s0;
        int s4 = (rem > 4) ? csr_src[i + 4] : s0;
        int s5 = (rem > 5) ? csr_src[i + 5] : s0;
        int s6 = (rem > 6) ? csr_src[i + 6] : s0;
        int s7 = (rem > 7) ? csr_src[i + 7] : s0;
        float a0 = asrc[s0 * 8 + h], a1 = asrc[s1 * 8 + h];
        float a2 = asrc[s2 * 8 + h], a3 = asrc[s3 * 8 + h];
        float a4 = asrc[s4 * 8 + h], a5 = asrc[s5 * 8 + h];
        float a6 = asrc[s6 * 8 + h], a7 = asrc[s7 * 8 + h];
        float4 v0 = x4[(size_t)s0 * 8 + kq], v1 = x4[(size_t)s1 * 8 + kq];
        float4 v2 = x4[(size_t)s2 * 8 + kq], v3 = x4[(size_t)s3 * 8 + kq];
        float4 v4 = x4[(size_t)s4 * 8 + kq], v5 = x4[(size_t)s5 * 8 + kq];
        float4 v6 = x4[(size_t)s6 * 8 + kq], v7 = x4[(size_t)s7 * 8 + kq];
        float e0 = __expf(lrelu(a0 + ad));
        float e1 = (rem > 1) ? __expf(lrelu(a1 + ad)) : 0.0f;
        float e2 = (rem > 2) ? __expf(lrelu(a2 + ad)) : 0.0f;
        float e3 = (rem > 3) ? __expf(lrelu(a3 + ad)) : 0.0f;
        float e4 = (rem > 4) ? __expf(lrelu(a4 + ad)) : 0.0f;
        float e5 = (rem > 5) ? __expf(lrelu(a5 + ad)) : 0.0f;
        float e6 = (rem > 6) ? __expf(lrelu(a6 + ad)) : 0.0f;
        float e7 = (rem > 7) ? __expf(lrelu(a7 + ad)) : 0.0f;
        acc.x += e0 * v0.x + e1 * v1.x + e2 * v2.x + e3 * v3.x
               + e4 * v4.x + e5 * v5.x + e6 * v6.x + e7 * v7.x;
        acc.y += e0 * v0.y + e1 * v1.y + e2 * v2.y + e3 * v3.y
               + e4 * v4.y + e5 * v5.y + e6 * v6.y + e7 * v7.y;
        acc.z += e0 * v0.z + e1 * v1.z + e2 * v2.z + e3 * v3.z
               + e4 * v4.z + e5 * v5.z + e6 * v6.z + e7 * v7.z;
        acc.w += e0 * v0.w + e1 * v1.w + e2 * v2.w + e3 * v3.w
               + e4 * v4.w + e5 * v5.w + e6 * v6.w + e7 * v7.w;
        den += ((e0 + e1) + (e2 + e3)) + ((e4 + e5) + (e6 + e7));
    }
    float inv = 1.0f / fmaxf(den, 1e-16f);
    float4 r = make_float4(acc.x * inv, acc.y * inv, acc.z * inv, acc.w * inv);
    ((float4*)z)[(size_t)w * 64 + lane] = r;
}

// ---------------- K5b: gatT[b][c][node] = z[node,:] @ M[:,c] + b_gat[c] ----------------
__global__ __launch_bounds__(256) void k_zw(
    const float* __restrict__ z, const float* __restrict__ W_gat,
    const float* __restrict__ b_gat, float* __restrict__ gatT, int N, int n_node) {
    int gw = (blockIdx.x * 256 + threadIdx.x) >> 6;  // 0..7999
    int lane = threadIdx.x & 63;
    int chalf = gw & 1;
    int nset = gw >> 1;                               // 0..3999
    int c = chalf * 16 + (lane & 15);
    int sl = lane >> 4;
    float wcol[64];
    #pragma unroll
    for (int i = 0; i < 64; ++i) {
        int k = i & 31, hh = sl * 2 + (i >> 5);
        wcol[i] = 0.125f * W_gat[k * 256 + hh * 32 + c];
    }
    float bg = b_gat[c];
    const float4* z4 = (const float4*)z;
    #pragma unroll 2
    for (int it = 0; it < 8; ++it) {
        int n = nset * 8 + it;   // always < N (grid covers exactly N/8 nsets)
        float p = 0.0f;
        #pragma unroll
        for (int k4 = 0; k4 < 16; ++k4) {
            float4 zv = z4[(size_t)n * 64 + sl * 16 + k4];
            p += zv.x * wcol[4 * k4] + zv.y * wcol[4 * k4 + 1]
               + zv.z * wcol[4 * k4 + 2] + zv.w * wcol[4 * k4 + 3];
        }
        p += __shfl_xor(p, 16, 64);
        p += __shfl_xor(p, 32, 64);
        if (lane < 16) {
            int b = n / n_node, kk = n - b * n_node;
            gatT[((size_t)b * 32 + c) * n_node + kk] = p + bg;
        }
    }
}

// ---------------- K6b: P1[t,b,g] = bias + dot(Wt[:, g], gatT[b][t][:]) ----------------
__global__ __launch_bounds__(256) void k_p1(
    const float* __restrict__ gatT, const float* __restrict__ Wt,
    const float* __restrict__ b_ih1, const float* __restrict__ b_hh1,
    float* __restrict__ P1, int n_node, int B) {
    __shared__ __align__(16) float Arow[2][1024];
    __shared__ __align__(16) float part[4][2][128];
    int blk = blockIdx.x;
    int b = blk >> 4;
    int tq = blk & 15;
    int tid = threadIdx.x;
    const float* A0 = gatT + ((size_t)b * 32 + tq * 2) * n_node;
    #pragma unroll
    for (int r = 0; r < 2; ++r)
        for (int i = tid; i < n_node; i += 256)
            Arow[r][i] = A0[(size_t)r * n_node + i];
    __syncthreads();

    int g4 = tid & 31;
    int tloc = (tid >> 5) & 1;
    int ks = tid >> 6;
    int kq = n_node >> 2;            // 250
    int k0 = ks * kq;
    const float4* Wt4 = (const float4*)Wt;
    float4 acc = make_float4(0.0f, 0.0f, 0.0f, 0.0f);
    #pragma unroll 4
    for (int k = 0; k < kq; ++k) {
        float4 w = Wt4[(size_t)(k0 + k) * 32 + g4];
        float a = Arow[tloc][k0 + k];
        acc.x += w.x * a; acc.y += w.y * a;
        acc.z += w.z * a; acc.w += w.w * a;
    }
    *(float4*)&part[ks][tloc][g4 * 4] = acc;
    __syncthreads();

    int tl = tid >> 7, g = tid & 127;
    float s = part[0][tl][g] + part[1][tl][g] + part[2][tl][g] + part[3][tl][g]
            + b_ih1[g] + b_hh1[g];
    int t = tq * 2 + tl;
    P1[((size_t)t * B + b) * 128 + g] = s;
}

// ---------------- K7: pipelined LSTM1 || LSTM2, 4-wave full-row, AGPR weights ----------------
// R12-R15 diagnosis: allocator grants ~124 VGPR < need => W_hh2 streamed from
// L2 every step (3480 cy/step). Fix: park the 128 weight dwords in the AGPR
// file via "=a" inline-asm constraints -- outside the VGPR pressure model.
// Per-step: 128 v_accvgpr_read + 224 v_dot2 (all VALU) ~ 1100 cy.
__global__ __launch_bounds__(256, 1) void k_lstm(
    const float* __restrict__ P1, const uint4* __restrict__ wc2p,
    const uint4* __restrict__ wi2p, const uint4* __restrict__ w1p,
    const float* __restrict__ b_ih2, const float* __restrict__ b_hh2,
    float* __restrict__ h2finT, int B, int T) {
    __shared__ __align__(16) float P1s[32][128];     // 16KB
    __shared__ __align__(16) __half h1buf[2][32];    // fp16 L1 state, dbuf
    __shared__ __align__(16) __half h2buf[2][128];   // fp16 L2 state, dbuf
    int t = threadIdx.x, b = blockIdx.x;
    int u = t >> 1, ht = t & 1;

    // stage P1
    for (int i = t; i < 1024; i += 256) {
        int tt = i >> 5, c4 = i & 31;
        ((float4*)P1s[tt])[c4] = ((const float4*)(P1 + ((size_t)tt * B + b) * 128))[c4];
    }

    // W_hh2 -> AGPR file (128 dwords), coalesced global loads
    unsigned rg0, rg1, rg2, rg3, rg4, rg5, rg6, rg7;
    unsigned rg8, rg9, rg10, rg11, rg12, rg13, rg14, rg15;
    unsigned rg16, rg17, rg18, rg19, rg20, rg21, rg22, rg23;
    unsigned rg24, rg25, rg26, rg27, rg28, rg29, rg30, rg31;
    unsigned rg32, rg33, rg34, rg35, rg36, rg37, rg38, rg39;
    unsigned rg40, rg41, rg42, rg43, rg44, rg45, rg46, rg47;
    unsigned rg48, rg49, rg50, rg51, rg52, rg53, rg54, rg55;
    unsigned rg56, rg57, rg58, rg59, rg60, rg61, rg62, rg63;
    unsigned rg64, rg65, rg66, rg67, rg68, rg69, rg70, rg71;
    unsigned rg72, rg73, rg74, rg75, rg76, rg77, rg78, rg79;
    unsigned rg80, rg81, rg82, rg83, rg84, rg85, rg86, rg87;
    unsigned rg88, rg89, rg90, rg91, rg92, rg93, rg94, rg95;
    unsigned rg96, rg97, rg98, rg99, rg100, rg101, rg102, rg103;
    unsigned rg104, rg105, rg106, rg107, rg108, rg109, rg110, rg111;
    unsigned rg112, rg113, rg114, rg115, rg116, rg117, rg118, rg119;
    unsigned rg120, rg121, rg122, rg123, rg124, rg125, rg126, rg127;
    {
        uint4 w;
        w = wc2p[0 * 256 + t];  AGW4(rg0, rg1, rg2, rg3, w);
        w = wc2p[1 * 256 + t];  AGW4(rg4, rg5, rg6, rg7, w);
        w = wc2p[2 * 256 + t];  AGW4(rg8, rg9, rg10, rg11, w);
        w = wc2p[3 * 256 + t];  AGW4(rg12, rg13, rg14, rg15, w);
        w = wc2p[4 * 256 + t];  AGW4(rg16, rg17, rg18, rg19, w);
        w = wc2p[5 * 256 + t];  AGW4(rg20, rg21, rg22, rg23, w);
        w = wc2p[6 * 256 + t];  AGW4(rg24, rg25, rg26, rg27, w);
        w = wc2p[7 * 256 + t];  AGW4(rg28, rg29, rg30, rg31, w);
        w = wc2p[8 * 256 + t];  AGW4(rg32, rg33, rg34, rg35, w);
        w = wc2p[9 * 256 + t];  AGW4(rg36, rg37, rg38, rg39, w);
        w = wc2p[10 * 256 + t]; AGW4(rg40, rg41, rg42, rg43, w);
        w = wc2p[11 * 256 + t]; AGW4(rg44, rg45, rg46, rg47, w);
        w = wc2p[12 * 256 + t]; AGW4(rg48, rg49, rg50, rg51, w);
        w = wc2p[13 * 256 + t]; AGW4(rg52, rg53, rg54, rg55, w);
        w = wc2p[14 * 256 + t]; AGW4(rg56, rg57, rg58, rg59, w);
        w = wc2p[15 * 256 + t]; AGW4(rg60, rg61, rg62, rg63, w);
        w = wc2p[16 * 256 + t]; AGW4(rg64, rg65, rg66, rg67, w);
        w = wc2p[17 * 256 + t]; AGW4(rg68, rg69, rg70, rg71, w);
        w = wc2p[18 * 256 + t]; AGW4(rg72, rg73, rg74, rg75, w);
        w = wc2p[19 * 256 + t]; AGW4(rg76, rg77, rg78, rg79, w);
        w = wc2p[20 * 256 + t]; AGW4(rg80, rg81, rg82, rg83, w);
        w = wc2p[21 * 256 + t]; AGW4(rg84, rg85, rg86, rg87, w);
        w = wc2p[22 * 256 + t]; AGW4(rg88, rg89, rg90, rg91, w);
        w = wc2p[23 * 256 + t]; AGW4(rg92, rg93, rg94, rg95, w);
        w = wc2p[24 * 256 + t]; AGW4(rg96, rg97, rg98, rg99, w);
        w = wc2p[25 * 256 + t]; AGW4(rg100, rg101, rg102, rg103, w);
        w = wc2p[26 * 256 + t]; AGW4(rg104, rg105, rg106, rg107, w);
        w = wc2p[27 * 256 + t]; AGW4(rg108, rg109, rg110, rg111, w);
        w = wc2p[28 * 256 + t]; AGW4(rg112, rg113, rg114, rg115, w);
        w = wc2p[29 * 256 + t]; AGW4(rg116, rg117, rg118, rg119, w);
        w = wc2p[30 * 256 + t]; AGW4(rg120, rg121, rg122, rg123, w);
        w = wc2p[31 * 256 + t]; AGW4(rg124, rg125, rg126, rg127, w);
    }
    uint4 wi[8];
    #pragma unroll
    for (int j = 0; j < 8; ++j) wi[j] = wi2p[j * 256 + t];
    uint4 w1[8];
    if (t < 64) {
        #pragma unroll
        for (int j = 0; j < 8; ++j) w1[j] = w1p[j * 64 + t];
    }
    int r0 = ht * 256 + u;            // row p=0
    int r1 = ht * 256 + 128 + u;      // row p=1
    float bias0 = b_ih2[r0] + b_hh2[r0];
    float bias1 = b_ih2[r1] + b_hh2[r1];

    if (t < 32) h1buf[0][t] = __float2half(0.0f);
    if (t < 128) h2buf[0][t] = __float2half(0.0f);
    float c1 = 0.0f, c2 = 0.0f;
    __syncthreads();

    for (int s = 0; s <= T; ++s) {
        const uint4* h1q = (const uint4*)h1buf[s & 1];
        uint4 hv0 = h1q[0], hv1 = h1q[1], hv2 = h1q[2], hv3 = h1q[3];

        // ---- LSTM2 step t2 = s-1 (all threads) ----
        if (s >= 1) {
            int t2 = s - 1;
            const uint4* hb = (const uint4*)h2buf[t2 & 1];
            float p0a, p0b, p1a, p1b;
            p0a = dot16(wi[0], hv0, 0.0f); p0b = dot16(wi[1], hv1, 0.0f);
            p0a = dot16(wi[2], hv2, p0a);  p0b = dot16(wi[3], hv3, p0b);
            p1a = dot16(wi[4], hv0, 0.0f); p1b = dot16(wi[5], hv1, 0.0f);
            p1a = dot16(wi[6], hv2, p1a);  p1b = dot16(wi[7], hv3, p1b);
            uint4 wA0, wA1, wA2, wA3, wB0, wB1, wB2, wB3;
            // chunk 0: wc[0..3] / wc[16..19]
            {
                uint4 h0 = hb[0], h1_ = hb[1], h2_ = hb[2], h3 = hb[3];
                AGR4(wA0, rg0, rg1, rg2, rg3);
                AGR4(wA1, rg4, rg5, rg6, rg7);
                AGR4(wA2, rg8, rg9, rg10, rg11);
                AGR4(wA3, rg12, rg13, rg14, rg15);
                AGR4(wB0, rg64, rg65, rg66, rg67);
                AGR4(wB1, rg68, rg69, rg70, rg71);
                AGR4(wB2, rg72, rg73, rg74, rg75);
                AGR4(wB3, rg76, rg77, rg78, rg79);
                p0a = dot16(wA0, h0, p0a);  p0b = dot16(wA1, h1_, p0b);
                p0a = dot16(wA2, h2_, p0a); p0b = dot16(wA3, h3, p0b);
                p1a = dot16(wB0, h0, p1a);  p1b = dot16(wB1, h1_, p1b);
                p1a = dot16(wB2, h2_, p1a); p1b = dot16(wB3, h3, p1b);
            }
            // chunk 1: wc[4..7] / wc[20..23]
            {
                uint4 h0 = hb[4], h1_ = hb[5], h2_ = hb[6], h3 = hb[7];
                AGR4(wA0, rg16, rg17, rg18, rg19);
                AGR4(wA1, rg20, rg21, rg22, rg23);
                AGR4(wA2, rg24, rg25, rg26, rg27);
                AGR4(wA3, rg28, rg29, rg30, rg31);
                AGR4(wB0, rg80, rg81, rg82, rg83);
                AGR4(wB1, rg84, rg85, rg86, rg87);
                AGR4(wB2, rg88, rg89, rg90, rg91);
                AGR4(wB3, rg92, rg93, rg94, rg95);
                p0a = dot16(wA0, h0, p0a);  p0b = dot16(wA1, h1_, p0b);
                p0a = dot16(wA2, h2_, p0a); p0b = dot16(wA3, h3, p0b);
                p1a = dot16(wB0, h0, p1a);  p1b = dot16(wB1, h1_, p1b);
                p1a = dot16(wB2, h2_, p1a); p1b = dot16(wB3, h3, p1b);
            }
            // chunk 2: wc[8..11] / wc[24..27]
            {
                uint4 h0 = hb[8], h1_ = hb[9], h2_ = hb[10], h3 = hb[11];
                AGR4(wA0, rg32, rg33, rg34, rg35);
                AGR4(wA1, rg36, rg37, rg38, rg39);
                AGR4(wA2, rg40, rg41, rg42, rg43);
                AGR4(wA3, rg44, rg45, rg46, rg47);
                AGR4(wB0, rg96, rg97, rg98, rg99);
                AGR4(wB1, rg100, rg101, rg102, rg103);
                AGR4(wB2, rg104, rg105, rg106, rg107);
                AGR4(wB3, rg108, rg109, rg110, rg111);
                p0a = dot16(wA0, h0, p0a);  p0b = dot16(wA1, h1_, p0b);
                p0a = dot16(wA2, h2_, p0a); p0b = dot16(wA3, h3, p0b);
                p1a = dot16(wB0, h0, p1a);  p1b = dot16(wB1, h1_, p1b);
                p1a = dot16(wB2, h2_, p1a); p1b = dot16(wB3, h3, p1b);
            }
            // chunk 3: wc[12..15] / wc[28..31]
            {
                uint4 h0 = hb[12], h1_ = hb[13], h2_ = hb[14], h3 = hb[15];
                AGR4(wA0, rg48, rg49, rg50, rg51);
                AGR4(wA1, rg52, rg53, rg54, rg55);
                AGR4(wA2, rg56, rg57, rg58, rg59);
                AGR4(wA3, rg60, rg61, rg62, rg63);
                AGR4(wB0, rg112, rg113, rg114, rg115);
                AGR4(wB1, rg116, rg117, rg118, rg119);
                AGR4(wB2, rg120, rg121, rg122, rg123);
                AGR4(wB3, rg124, rg125, rg126, rg127);
                p0a = dot16(wA0, h0, p0a);  p0b = dot16(wA1, h1_, p0b);
                p0a = dot16(wA2, h2_, p0a); p0b = dot16(wA3, h3, p0b);
                p1a = dot16(wB0, h0, p1a);  p1b = dot16(wB1, h1_, p1b);
                p1a = dot16(wB2, h2_, p1a); p1b = dot16(wB3, h3, p1b);
            }
            float s0 = p0a + p0b + bias0;   // ht=0: gate i | ht=1: gate g
            float s1 = p1a + p1b + bias1;   // ht=0: gate f | ht=1: gate o
            float o0 = __shfl_xor(s0, 1, 64);
            float o1 = __shfl_xor(s1, 1, 64);
            float gi = (ht == 0) ? s0 : o0;
            float gf = (ht == 0) ? s1 : o1;
            float gg = (ht == 0) ? o0 : s0;
            float go = (ht == 0) ? o1 : s1;
            c2 = sigm(gf) * c2 + sigm(gi) * tanh_fast(gg);
            float h = sigm(go) * tanh_fast(c2);
            if (ht == 0) {
                h2buf[(t2 + 1) & 1][u] = __float2half(h);
                if (t2 == T - 1) h2finT[u * 32 + b] = h;
            }
        }
        // ---- LSTM1 step s (wave 0 only) ----
        if (t < 64 && s < T) {
            float aA = P1s[s][t];
            float aB = P1s[s][64 + t];
            aA = dot16(w1[0], hv0, aA); aA = dot16(w1[1], hv1, aA);
            aA = dot16(w1[2], hv2, aA); aA = dot16(w1[3], hv3, aA);
            aB = dot16(w1[4], hv0, aB); aB = dot16(w1[5], hv1, aB);
            aB = dot16(w1[6], hv2, aB); aB = dot16(w1[7], hv3, aB);
            float oA = __shfl_xor(aA, 32, 64);
            float oB = __shfl_xor(aB, 32, 64);
            float gi = (t < 32) ? aA : oA;
            float gf = (t < 32) ? oA : aA;
            float gg = (t < 32) ? aB : oB;
            float go = (t < 32) ? oB : aB;
            c1 = sigm(gf) * c1 + sigm(gi) * tanh_fast(gg);
            float h = sigm(go) * tanh_fast(c1);
            if (t < 32) h1buf[(s + 1) & 1][t] = __float2half(h);
        }
        __syncthreads();
    }
}

// ---------------- K8: final linear from h2finT ----------------
__global__ __launch_bounds__(256) void k_fin(
    const float* __restrict__ h2finT, const float* __restrict__ W_lin,
    const float* __restrict__ b_lin, float* __restrict__ out, int n_node, int B) {
    __shared__ __align__(16) float hs[128];
    int b = blockIdx.x >> 3;
    int kc = blockIdx.x & 7;
    int tid = threadIdx.x;
    if (tid < 128) hs[tid] = h2finT[tid * 32 + b];
    __syncthreads();
    int outdim = n_node * 2;
    int kk = kc * 256 + tid;
    if (kk < outdim) {
        float acc = b_lin[kk];
        const float4* W4 = (const float4*)(W_lin + (size_t)kk * 128);
        const float4* h4 = (const float4*)hs;
        #pragma unroll 8
        for (int j = 0; j < 32; ++j) {
            float4 w = W4[j], h = h4[j];
            acc += w.x * h.x + w.y * h.y + w.z * h.z + w.w * h.w;
        }
        out[(size_t)b * outdim + kk] = acc;
    }
}

extern "C" void kernel_launch(void* const* d_in, const int* in_sizes, int n_in,
                              void* d_out, int out_size, void* d_ws, size_t ws_size,
                              hipStream_t stream) {
    const float* x     = (const float*)d_in[0];
    const int*   src   = (const int*)d_in[1];
    const int*   dst   = (const int*)d_in[2];
    const float* W_gat = (const float*)d_in[4];
    const float* a_src = (const float*)d_in[5];
    const float* a_dst = (const float*)d_in[6];
    const float* b_gat = (const float*)d_in[7];
    const float* W_ih1 = (const float*)d_in[8];
    const float* W_hh1 = (const float*)d_in[9];
    const float* b_ih1 = (const float*)d_in[10];
    const float* b_hh1 = (const float*)d_in[11];
    const float* W_ih2 = (const float*)d_in[12];
    const float* W_hh2 = (const float*)d_in[13];
    const float* b_ih2 = (const float*)d_in[14];
    const float* b_hh2 = (const float*)d_in[15];
    const float* W_lin = (const float*)d_in[16];
    const float* b_lin = (const float*)d_in[17];

    int N = in_sizes[0] / 32;          // 32000
    int E = in_sizes[1];               // 384000
    int n_node = in_sizes[8] / 128;    // 1000
    int B = N / n_node;                // 32
    int T = 32;

    float* ws = (float*)d_ws;
    float* z      = ws;                                 // N*256
    float* asrc   = z + (size_t)N * 256;                // N*8
    float* adst   = asrc + (size_t)N * 8;               // N*8
    float* gatT   = adst + (size_t)N * 8;               // N*32
    float* P1     = gatT + (size_t)N * 32;              // T*B*128
    float* wc2f   = P1 + (size_t)T * B * 128;           // 8192 uint4 = 32768 f32
    float* wiff   = wc2f + 32768;                       // 2048 uint4 = 8192 f32
    float* w1ff   = wiff + 8192;                        // 512 uint4 = 2048 f32
    float* h2finT = w1ff + 2048;                        // 128*32
    float* wa     = h2finT + 128 * 32;                  // 512
    int* deg     = (int*)(wa + 512);                    // N
    int* cursor  = deg + N;                             // N
    int* rowptr  = cursor + N;                          // N+1
    int* csr_src = rowptr + N + 1;                      // E
    int* blksum  = csr_src + E;                         // 256
    int* blkoff  = blksum + 256;                        // 256
    float* Wt    = (float*)(((uintptr_t)(blkoff + 256) + 255) & ~(uintptr_t)255); // n_node*128

    uint4* wc2p = (uint4*)wc2f;
    uint4* wi2p = (uint4*)wiff;
    uint4* w1p  = (uint4*)w1ff;

    int nb = (N + 255) / 256;   // 125

    k_prep<<<171 + nb, 256, 0, stream>>>(W_ih1, Wt, n_node, W_hh2, W_ih2, W_hh1,
                                         wc2p, wi2p, w1p, W_gat, a_src, a_dst,
                                         wa, deg, N);
    k_hist<<<(E + 255) / 256, 256, 0, stream>>>(dst, deg, E);
    k_scan1<<<nb, 256, 0, stream>>>(deg, blksum, N);
    k_scan2<<<1, 256, 0, stream>>>(blksum, blkoff, nb);
    k_scan3<<<nb, 256, 0, stream>>>(deg, blkoff, rowptr, cursor, N, E);
    k_scatter<<<(E + 255) / 256, 256, 0, stream>>>(src, dst, cursor, csr_src, E);
    k_att<<<N / 32, 256, 0, stream>>>(x, wa, asrc, adst);
    k_gat<<<(N * 64 + 255) / 256, 256, 0, stream>>>(rowptr, csr_src, asrc, adst,
                                                    x, z, N);
    k_zw<<<2000, 256, 0, stream>>>(z, W_gat, b_gat, gatT, N, n_node);
    k_p1<<<B * 16, 256, 0, stream>>>(gatT, Wt, b_ih1, b_hh1, P1, n_node, B);
    k_lstm<<<B, 256, 0, stream>>>(P1, wc2p, wi2p, w1p, b_ih2, b_hh2, h2finT, B, T);
    k_fin<<<B * 8, 256, 0, stream>>>(h2finT, W_lin, b_lin, (float*)d_out, n_node, B);
}

// Round 17
// 198.751 us; speedup vs baseline: 1.0704x; 1.0704x over previous
//
#include <hip/hip_runtime.h>
#include <hip/hip_fp16.h>
#include <math.h>

#define NEG_SLOPE 0.2f

__device__ __forceinline__ float sigm(float x) { return 1.0f / (1.0f + __expf(-x)); }
__device__ __forceinline__ float tanh_fast(float x) {
    float xc = fminf(fmaxf(x, -15.0f), 15.0f);
    float e2 = __expf(2.0f * xc);
    return (e2 - 1.0f) / (e2 + 1.0f);
}
__device__ __forceinline__ float lrelu(float x) { return (x > 0.0f) ? x : NEG_SLOPE * x; }

typedef _Float16 h2v __attribute__((ext_vector_type(2)));
__device__ __forceinline__ float fdot2h(h2v a, h2v b, float c) {
#if __has_builtin(__builtin_amdgcn_fdot2)
    return __builtin_amdgcn_fdot2(a, b, c, false);
#else
    return (float)a[0] * (float)b[0] + (float)a[1] * (float)b[1] + c;
#endif
}

// dot over 8 fp16 dims held as uint4 (4 x v_dot2)
__device__ __forceinline__ float dot16(const uint4& w, const uint4& h, float acc) {
    const h2v* wp = reinterpret_cast<const h2v*>(&w);
    const h2v* hp = reinterpret_cast<const h2v*>(&h);
    acc = fdot2h(wp[0], hp[0], acc);
    acc = fdot2h(wp[1], hp[1], acc);
    acc = fdot2h(wp[2], hp[2], acc);
    acc = fdot2h(wp[3], hp[3], acc);
    return acc;
}

// ---------------- K1: histogram of dst ----------------
__global__ void k_hist(const int* __restrict__ dst, int* __restrict__ deg, int E) {
    int e = blockIdx.x * 256 + threadIdx.x;
    if (e < E) atomicAdd(deg + dst[e], 1);
}

// ---------------- scan (3 kernels, multi-block) ----------------
__global__ __launch_bounds__(256) void k_scan1(const int* __restrict__ deg,
                                               int* __restrict__ blksum, int N) {
    __shared__ int s[256];
    int tid = threadIdx.x;
    int i = blockIdx.x * 256 + tid;
    int v = (i < N) ? deg[i] : 0;
    s[tid] = v;
    __syncthreads();
    #pragma unroll
    for (int off = 128; off > 0; off >>= 1) {
        if (tid < off) s[tid] += s[tid + off];
        __syncthreads();
    }
    if (tid == 0) blksum[blockIdx.x] = s[0];
}

__global__ __launch_bounds__(256) void k_scan2(const int* __restrict__ blksum,
                                               int* __restrict__ blkoff, int nb) {
    __shared__ int s[256];
    int tid = threadIdx.x;
    int v = (tid < nb) ? blksum[tid] : 0;
    s[tid] = v;
    __syncthreads();
    for (int off = 1; off < 256; off <<= 1) {
        int t = (tid >= off) ? s[tid - off] : 0;
        __syncthreads();
        s[tid] += t;
        __syncthreads();
    }
    if (tid < nb) blkoff[tid] = s[tid] - v;   // exclusive
}

__global__ __launch_bounds__(256) void k_scan3(const int* __restrict__ deg,
                                               const int* __restrict__ blkoff,
                                               int* __restrict__ rowptr,
                                               int* __restrict__ cursor, int N, int E) {
    __shared__ int s[256];
    int tid = threadIdx.x;
    int i = blockIdx.x * 256 + tid;
    int v = (i < N) ? deg[i] : 0;
    s[tid] = v;
    __syncthreads();
    for (int off = 1; off < 256; off <<= 1) {
        int t = (tid >= off) ? s[tid - off] : 0;
        __syncthreads();
        s[tid] += t;
        __syncthreads();
    }
    int excl = s[tid] - v + blkoff[blockIdx.x];
    if (i < N) { rowptr[i] = excl; cursor[i] = excl; }
    if (i == N - 1) rowptr[N] = E;
}

// ---------------- K3: scatter edges into CSR (by dst) ----------------
__global__ void k_scatter(const int* __restrict__ src, const int* __restrict__ dst,
                          int* __restrict__ cursor, int* __restrict__ csr_src, int E) {
    int e = blockIdx.x * 256 + threadIdx.x;
    if (e < E) {
        int pos = atomicAdd(cursor + dst[e], 1);
        csr_src[pos] = src[e];
    }
}

// ---------------- K_PREP: fused {k_wt | k_pack2 | k_pre | k_zero} by block range ----------------
// blocks [0,128): transpose W_ih1 -> Wt ; [128,170): pack LSTM weights ;
// block 170: wa precompute ; [171,171+nbN): zero deg.
__global__ __launch_bounds__(256) void k_prep(
    const float* __restrict__ W_ih1, float* __restrict__ Wt, int n_node,
    const float* __restrict__ W_hh2, const float* __restrict__ W_ih2,
    const float* __restrict__ W_hh1,
    uint4* __restrict__ wc2p, uint4* __restrict__ wi2p, uint4* __restrict__ w1p,
    const float* __restrict__ W_gat, const float* __restrict__ a_src,
    const float* __restrict__ a_dst, float* __restrict__ wa,
    int* __restrict__ deg, int N) {
    int blk = blockIdx.x, tid = threadIdx.x;
    if (blk < 128) {
        __shared__ float tle[32][33];
        int kt = blk & 31;
        int gt = blk >> 5;
        for (int i = tid; i < 1024; i += 256) {
            int gl = i >> 5, kl = i & 31;
            int g = gt * 32 + gl, k = kt * 32 + kl;
            tle[gl][kl] = (k < n_node) ? W_ih1[(size_t)g * n_node + k] : 0.0f;
        }
        __syncthreads();
        for (int i = tid; i < 1024; i += 256) {
            int kl = i >> 5, gl = i & 31;
            int k = kt * 32 + kl, g = gt * 32 + gl;
            if (k < n_node) Wt[(size_t)k * 128 + g] = tle[gl][kl];
        }
    } else if (blk < 170) {
        int i = (blk - 128) * 256 + tid;   // 0..10751
        __align__(16) _Float16 tmp[8];
        if (i < 8192) {
            int jj = i >> 8, t = i & 255;
            int p = jj >> 4, j = jj & 15;
            int r = (t & 1) * 256 + p * 128 + (t >> 1);
            const float* s = W_hh2 + (size_t)r * 128 + j * 8;
            #pragma unroll
            for (int k = 0; k < 8; ++k) tmp[k] = (_Float16)s[k];
            wc2p[jj * 256 + t] = *(const uint4*)tmp;
        } else if (i < 10240) {
            int ii = i - 8192;
            int jj = ii >> 8, t = ii & 255;
            int p = jj >> 2, j = jj & 3;
            int r = (t & 1) * 256 + p * 128 + (t >> 1);
            const float* s = W_ih2 + (size_t)r * 32 + j * 8;
            #pragma unroll
            for (int k = 0; k < 8; ++k) tmp[k] = (_Float16)s[k];
            wi2p[jj * 256 + t] = *(const uint4*)tmp;
        } else if (i < 10752) {
            int ii = i - 10240;
            int jj = ii >> 6, l = ii & 63;
            int p = jj >> 2, j = jj & 3;
            int r = p * 64 + l;
            const float* s = W_hh1 + (size_t)r * 32 + j * 8;
            #pragma unroll
            for (int k = 0; k < 8; ++k) tmp[k] = (_Float16)s[k];
            w1p[jj * 64 + l] = *(const uint4*)tmp;
        }
    } else if (blk == 170) {
        int k = tid >> 3, h = tid & 7;
        float s1 = 0.0f, s2 = 0.0f;
        for (int c = 0; c < 32; ++c) {
            float wv = W_gat[k * 256 + h * 32 + c];
            s1 += wv * a_src[h * 32 + c];
            s2 += wv * a_dst[h * 32 + c];
        }
        wa[tid] = s1;
        wa[256 + tid] = s2;
    } else {
        int i = (blk - 171) * 256 + tid;
        if (i < N) deg[i] = 0;
    }
}

// ---------------- K4b: asrc/adst = x @ wa ----------------
__global__ __launch_bounds__(256) void k_att(const float* __restrict__ x,
                                             const float* __restrict__ wa,
                                             float* __restrict__ asrc,
                                             float* __restrict__ adst) {
    __shared__ float xs[32 * 33];
    __shared__ float was[256], wad[256];
    int tid = threadIdx.x;
    int n0 = blockIdx.x * 32;
    for (int i = tid; i < 1024; i += 256) {
        int nl = i >> 5, k = i & 31;
        xs[nl * 33 + k] = x[(size_t)(n0 + nl) * 32 + k];
    }
    was[tid] = wa[tid];
    wad[tid] = wa[256 + tid];
    __syncthreads();
    int nl = tid >> 3, h = tid & 7;
    float s1 = 0.0f, s2 = 0.0f;
    #pragma unroll
    for (int k = 0; k < 32; ++k) {
        float xv = xs[nl * 33 + k];
        s1 += xv * was[k * 8 + h];
        s2 += xv * wad[k * 8 + h];
    }
    asrc[(size_t)(n0 + nl) * 8 + h] = s1;
    adst[(size_t)(n0 + nl) * 8 + h] = s2;
}

// ---------------- K5: GAT gather, 8-deep MLP chunks ----------------
__global__ __launch_bounds__(256) void k_gat(
    const int* __restrict__ rowptr, const int* __restrict__ csr_src,
    const float* __restrict__ asrc, const float* __restrict__ adst,
    const float* __restrict__ x, float* __restrict__ z, int N) {
    int w = (blockIdx.x * 256 + threadIdx.x) >> 6;
    int lane = threadIdx.x & 63;
    if (w >= N) return;
    int r0 = rowptr[w], r1 = rowptr[w + 1];
    int h = lane >> 3, kq = lane & 7;
    float ad = adst[w * 8 + h];
    float4 acc = make_float4(0.0f, 0.0f, 0.0f, 0.0f);
    float den = 0.0f;
    const float4* x4 = (const float4*)x;
    for (int i = r0; i < r1; i += 8) {
        int rem = r1 - i;
        int s0 = csr_src[i];
        int s1 = (rem > 1) ? csr_src[i + 1] : s0;
        int s2 = (rem > 2) ? csr_src[i + 2] : s0;
        int s3 = (rem > 3) ? csr_src[i + 3] : s0;
        int s4 = (rem > 4) ? csr_src[i + 4] : s0;
        int s5 = (rem > 5) ? csr_src[i + 5] : s0;
        int s6 = (rem > 6) ? csr_src[i + 6] : s0;
        int s7 = (rem > 7) ? csr_src[i + 7] : s0;
        float a0 = asrc[s0 * 8 + h], a1 = asrc[s1 * 8 + h];
        float a2 = asrc[s2 * 8 + h], a3 = asrc[s3 * 8 + h];
        float a4 = asrc[s4 * 8 + h], a5 = asrc[s5 * 8 + h];
        float a6 = asrc[s6 * 8 + h], a7 = asrc[s7 * 8 + h];
        float4 v0 = x4[(size_t)s0 * 8 + kq], v1 = x4[(size_t)s1 * 8 + kq];
        float4 v2 = x4[(size_t)s2 * 8 + kq], v3 = x4[(size_t)s3 * 8 + kq];
        float4 v4 = x4[(size_t)s4 * 8 + kq], v5 = x4[(size_t)s5 * 8 + kq];
        float4 v6 = x4[(size_t)s6 * 8 + kq], v7 = x4[(size_t)s7 * 8 + kq];
        float e0 = __expf(lrelu(a0 + ad));
        float e1 = (rem > 1) ? __expf(lrelu(a1 + ad)) : 0.0f;
        float e2 = (rem > 2) ? __expf(lrelu(a2 + ad)) : 0.0f;
        float e3 = (rem > 3) ? __expf(lrelu(a3 + ad)) : 0.0f;
        float e4 = (rem > 4) ? __expf(lrelu(a4 + ad)) : 0.0f;
        float e5 = (rem > 5) ? __expf(lrelu(a5 + ad)) : 0.0f;
        float e6 = (rem > 6) ? __expf(lrelu(a6 + ad)) : 0.0f;
        float e7 = (rem > 7) ? __expf(lrelu(a7 + ad)) : 0.0f;
        acc.x += e0 * v0.x + e1 * v1.x + e2 * v2.x + e3 * v3.x
               + e4 * v4.x + e5 * v5.x + e6 * v6.x + e7 * v7.x;
        acc.y += e0 * v0.y + e1 * v1.y + e2 * v2.y + e3 * v3.y
               + e4 * v4.y + e5 * v5.y + e6 * v6.y + e7 * v7.y;
        acc.z += e0 * v0.z + e1 * v1.z + e2 * v2.z + e3 * v3.z
               + e4 * v4.z + e5 * v5.z + e6 * v6.z + e7 * v7.z;
        acc.w += e0 * v0.w + e1 * v1.w + e2 * v2.w + e3 * v3.w
               + e4 * v4.w + e5 * v5.w + e6 * v6.w + e7 * v7.w;
        den += ((e0 + e1) + (e2 + e3)) + ((e4 + e5) + (e6 + e7));
    }
    float inv = 1.0f / fmaxf(den, 1e-16f);
    float4 r = make_float4(acc.x * inv, acc.y * inv, acc.z * inv, acc.w * inv);
    ((float4*)z)[(size_t)w * 64 + lane] = r;
}

// ---------------- K5b: gatT[b][c][node] = z[node,:] @ M[:,c] + b_gat[c] ----------------
__global__ __launch_bounds__(256) void k_zw(
    const float* __restrict__ z, const float* __restrict__ W_gat,
    const float* __restrict__ b_gat, float* __restrict__ gatT, int N, int n_node) {
    int gw = (blockIdx.x * 256 + threadIdx.x) >> 6;  // 0..7999
    int lane = threadIdx.x & 63;
    int chalf = gw & 1;
    int nset = gw >> 1;                               // 0..3999
    int c = chalf * 16 + (lane & 15);
    int sl = lane >> 4;
    float wcol[64];
    #pragma unroll
    for (int i = 0; i < 64; ++i) {
        int k = i & 31, hh = sl * 2 + (i >> 5);
        wcol[i] = 0.125f * W_gat[k * 256 + hh * 32 + c];
    }
    float bg = b_gat[c];
    const float4* z4 = (const float4*)z;
    #pragma unroll 2
    for (int it = 0; it < 8; ++it) {
        int n = nset * 8 + it;   // always < N (grid covers exactly N/8 nsets)
        float p = 0.0f;
        #pragma unroll
        for (int k4 = 0; k4 < 16; ++k4) {
            float4 zv = z4[(size_t)n * 64 + sl * 16 + k4];
            p += zv.x * wcol[4 * k4] + zv.y * wcol[4 * k4 + 1]
               + zv.z * wcol[4 * k4 + 2] + zv.w * wcol[4 * k4 + 3];
        }
        p += __shfl_xor(p, 16, 64);
        p += __shfl_xor(p, 32, 64);
        if (lane < 16) {
            int b = n / n_node, kk = n - b * n_node;
            gatT[((size_t)b * 32 + c) * n_node + kk] = p + bg;
        }
    }
}

// ---------------- K6b: P1[t,b,g] = bias + dot(Wt[:, g], gatT[b][t][:]) ----------------
__global__ __launch_bounds__(256) void k_p1(
    const float* __restrict__ gatT, const float* __restrict__ Wt,
    const float* __restrict__ b_ih1, const float* __restrict__ b_hh1,
    float* __restrict__ P1, int n_node, int B) {
    __shared__ __align__(16) float Arow[2][1024];
    __shared__ __align__(16) float part[4][2][128];
    int blk = blockIdx.x;
    int b = blk >> 4;
    int tq = blk & 15;
    int tid = threadIdx.x;
    const float* A0 = gatT + ((size_t)b * 32 + tq * 2) * n_node;
    #pragma unroll
    for (int r = 0; r < 2; ++r)
        for (int i = tid; i < n_node; i += 256)
            Arow[r][i] = A0[(size_t)r * n_node + i];
    __syncthreads();

    int g4 = tid & 31;
    int tloc = (tid >> 5) & 1;
    int ks = tid >> 6;
    int kq = n_node >> 2;            // 250
    int k0 = ks * kq;
    const float4* Wt4 = (const float4*)Wt;
    float4 acc = make_float4(0.0f, 0.0f, 0.0f, 0.0f);
    #pragma unroll 4
    for (int k = 0; k < kq; ++k) {
        float4 w = Wt4[(size_t)(k0 + k) * 32 + g4];
        float a = Arow[tloc][k0 + k];
        acc.x += w.x * a; acc.y += w.y * a;
        acc.z += w.z * a; acc.w += w.w * a;
    }
    *(float4*)&part[ks][tloc][g4 * 4] = acc;
    __syncthreads();

    int tl = tid >> 7, g = tid & 127;
    float s = part[0][tl][g] + part[1][tl][g] + part[2][tl][g] + part[3][tl][g]
            + b_ih1[g] + b_hh1[g];
    int t = tq * 2 + tl;
    P1[((size_t)t * B + b) * 128 + g] = s;
}

// ---------------- K7: pipelined LSTM1 || LSTM2, 4-wave full-row (R12-proven, 46.5us) ----------------
// Final form. Placement ledger: all-reg 46.5 < hybrid 51.4 < all-LDS 56.4 <
// AGPR 59.9. Serial 33-step recurrence on 32 blocks; the L2 weight stream is
// the cheapest tier hipcc will emit and 5 mechanisms failed to change it.
__global__ __launch_bounds__(256, 1) void k_lstm(
    const float* __restrict__ P1, const uint4* __restrict__ wc2p,
    const uint4* __restrict__ wi2p, const uint4* __restrict__ w1p,
    const float* __restrict__ b_ih2, const float* __restrict__ b_hh2,
    float* __restrict__ h2finT, int B, int T) {
    __shared__ __align__(16) float P1s[32][128];     // 16KB
    __shared__ __align__(16) __half h1buf[2][32];    // fp16 L1 state, dbuf
    __shared__ __align__(16) __half h2buf[2][128];   // fp16 L2 state, dbuf
    int t = threadIdx.x, b = blockIdx.x;
    int u = t >> 1, ht = t & 1;

    // stage P1
    for (int i = t; i < 1024; i += 256) {
        int tt = i >> 5, c4 = i & 31;
        ((float4*)P1s[tt])[c4] = ((const float4*)(P1 + ((size_t)tt * B + b) * 128))[c4];
    }
    // weights: coalesced preload
    uint4 wc[32];
    #pragma unroll
    for (int j = 0; j < 32; ++j) wc[j] = wc2p[j * 256 + t];
    uint4 wi[8];
    #pragma unroll
    for (int j = 0; j < 8; ++j) wi[j] = wi2p[j * 256 + t];
    uint4 w1[8];
    if (t < 64) {
        #pragma unroll
        for (int j = 0; j < 8; ++j) w1[j] = w1p[j * 64 + t];
    }
    int r0 = ht * 256 + u;            // row p=0
    int r1 = ht * 256 + 128 + u;      // row p=1
    float bias0 = b_ih2[r0] + b_hh2[r0];
    float bias1 = b_ih2[r1] + b_hh2[r1];

    // init state
    if (t < 32) h1buf[0][t] = __float2half(0.0f);
    if (t < 128) h2buf[0][t] = __float2half(0.0f);
    float c1 = 0.0f, c2 = 0.0f;
    __syncthreads();

    for (int s = 0; s <= T; ++s) {
        // shared h1 read: h1buf[s&1] = h1[s-1] (zeros at s=0)
        const uint4* h1q = (const uint4*)h1buf[s & 1];
        uint4 hv0 = h1q[0], hv1 = h1q[1], hv2 = h1q[2], hv3 = h1q[3];

        // ---- LSTM2 step t2 = s-1 (all threads) ----
        if (s >= 1) {
            int t2 = s - 1;
            const uint4* hb = (const uint4*)h2buf[t2 & 1];
            // input projection (fp16 dot2): rows p=0,1
            float p0a, p0b, p1a, p1b;
            p0a = dot16(wi[0], hv0, 0.0f); p0b = dot16(wi[1], hv1, 0.0f);
            p0a = dot16(wi[2], hv2, p0a);  p0b = dot16(wi[3], hv3, p0b);
            p1a = dot16(wi[4], hv0, 0.0f); p1b = dot16(wi[5], hv1, 0.0f);
            p1a = dot16(wi[6], hv2, p1a);  p1b = dot16(wi[7], hv3, p1b);
            // recurrent 128-dot, chunked h2 reads (4 uint4 live at a time)
            #pragma unroll
            for (int c = 0; c < 4; ++c) {
                uint4 h0 = hb[c * 4], h1_ = hb[c * 4 + 1];
                uint4 h2_ = hb[c * 4 + 2], h3 = hb[c * 4 + 3];
                p0a = dot16(wc[c * 4], h0, p0a);
                p0b = dot16(wc[c * 4 + 1], h1_, p0b);
                p0a = dot16(wc[c * 4 + 2], h2_, p0a);
                p0b = dot16(wc[c * 4 + 3], h3, p0b);
                p1a = dot16(wc[16 + c * 4], h0, p1a);
                p1b = dot16(wc[16 + c * 4 + 1], h1_, p1b);
                p1a = dot16(wc[16 + c * 4 + 2], h2_, p1a);
                p1b = dot16(wc[16 + c * 4 + 3], h3, p1b);
            }
            float s0 = p0a + p0b + bias0;   // ht=0: gate i | ht=1: gate g
            float s1 = p1a + p1b + bias1;   // ht=0: gate f | ht=1: gate o
            float o0 = __shfl_xor(s0, 1, 64);
            float o1 = __shfl_xor(s1, 1, 64);
            float gi = (ht == 0) ? s0 : o0;
            float gf = (ht == 0) ? s1 : o1;
            float gg = (ht == 0) ? o0 : s0;
            float go = (ht == 0) ? o1 : s1;
            c2 = sigm(gf) * c2 + sigm(gi) * tanh_fast(gg);
            float h = sigm(go) * tanh_fast(c2);
            if (ht == 0) {
                h2buf[(t2 + 1) & 1][u] = __float2half(h);
                if (t2 == T - 1) h2finT[u * 32 + b] = h;
            }
        }
        // ---- LSTM1 step s (wave 0 only) ----
        if (t < 64 && s < T) {
            float aA = P1s[s][t];
            float aB = P1s[s][64 + t];
            aA = dot16(w1[0], hv0, aA); aA = dot16(w1[1], hv1, aA);
            aA = dot16(w1[2], hv2, aA); aA = dot16(w1[3], hv3, aA);
            aB = dot16(w1[4], hv0, aB); aB = dot16(w1[5], hv1, aB);
            aB = dot16(w1[6], hv2, aB); aB = dot16(w1[7], hv3, aB);
            float oA = __shfl_xor(aA, 32, 64);
            float oB = __shfl_xor(aB, 32, 64);
            float gi = (t < 32) ? aA : oA;
            float gf = (t < 32) ? oA : aA;
            float gg = (t < 32) ? aB : oB;
            float go = (t < 32) ? oB : aB;
            c1 = sigm(gf) * c1 + sigm(gi) * tanh_fast(gg);
            float h = sigm(go) * tanh_fast(c1);
            if (t < 32) h1buf[(s + 1) & 1][t] = __float2half(h);
        }
        __syncthreads();
    }
}

// ---------------- K8: final linear from h2finT ----------------
__global__ __launch_bounds__(256) void k_fin(
    const float* __restrict__ h2finT, const float* __restrict__ W_lin,
    const float* __restrict__ b_lin, float* __restrict__ out, int n_node, int B) {
    __shared__ __align__(16) float hs[128];
    int b = blockIdx.x >> 3;
    int kc = blockIdx.x & 7;
    int tid = threadIdx.x;
    if (tid < 128) hs[tid] = h2finT[tid * 32 + b];
    __syncthreads();
    int outdim = n_node * 2;
    int kk = kc * 256 + tid;
    if (kk < outdim) {
        float acc = b_lin[kk];
        const float4* W4 = (const float4*)(W_lin + (size_t)kk * 128);
        const float4* h4 = (const float4*)hs;
        #pragma unroll 8
        for (int j = 0; j < 32; ++j) {
            float4 w = W4[j], h = h4[j];
            acc += w.x * h.x + w.y * h.y + w.z * h.z + w.w * h.w;
        }
        out[(size_t)b * outdim + kk] = acc;
    }
}

extern "C" void kernel_launch(void* const* d_in, const int* in_sizes, int n_in,
                              void* d_out, int out_size, void* d_ws, size_t ws_size,
                              hipStream_t stream) {
    const float* x     = (const float*)d_in[0];
    const int*   src   = (const int*)d_in[1];
    const int*   dst   = (const int*)d_in[2];
    const float* W_gat = (const float*)d_in[4];
    const float* a_src = (const float*)d_in[5];
    const float* a_dst = (const float*)d_in[6];
    const float* b_gat = (const float*)d_in[7];
    const float* W_ih1 = (const float*)d_in[8];
    const float* W_hh1 = (const float*)d_in[9];
    const float* b_ih1 = (const float*)d_in[10];
    const float* b_hh1 = (const float*)d_in[11];
    const float* W_ih2 = (const float*)d_in[12];
    const float* W_hh2 = (const float*)d_in[13];
    const float* b_ih2 = (const float*)d_in[14];
    const float* b_hh2 = (const float*)d_in[15];
    const float* W_lin = (const float*)d_in[16];
    const float* b_lin = (const float*)d_in[17];

    int N = in_sizes[0] / 32;          // 32000
    int E = in_sizes[1];               // 384000
    int n_node = in_sizes[8] / 128;    // 1000
    int B = N / n_node;                // 32
    int T = 32;

    float* ws = (float*)d_ws;
    float* z      = ws;                                 // N*256
    float* asrc   = z + (size_t)N * 256;                // N*8
    float* adst   = asrc + (size_t)N * 8;               // N*8
    float* gatT   = adst + (size_t)N * 8;               // N*32
    float* P1     = gatT + (size_t)N * 32;              // T*B*128
    float* wc2f   = P1 + (size_t)T * B * 128;           // 8192 uint4 = 32768 f32
    float* wiff   = wc2f + 32768;                       // 2048 uint4 = 8192 f32
    float* w1ff   = wiff + 8192;                        // 512 uint4 = 2048 f32
    float* h2finT = w1ff + 2048;                        // 128*32
    float* wa     = h2finT + 128 * 32;                  // 512
    int* deg     = (int*)(wa + 512);                    // N
    int* cursor  = deg + N;                             // N
    int* rowptr  = cursor + N;                          // N+1
    int* csr_src = rowptr + N + 1;                      // E
    int* blksum  = csr_src + E;                         // 256
    int* blkoff  = blksum + 256;                        // 256
    float* Wt    = (float*)(((uintptr_t)(blkoff + 256) + 255) & ~(uintptr_t)255); // n_node*128

    uint4* wc2p = (uint4*)wc2f;
    uint4* wi2p = (uint4*)wiff;
    uint4* w1p  = (uint4*)w1ff;

    int nb = (N + 255) / 256;   // 125

    k_prep<<<171 + nb, 256, 0, stream>>>(W_ih1, Wt, n_node, W_hh2, W_ih2, W_hh1,
                                         wc2p, wi2p, w1p, W_gat, a_src, a_dst,
                                         wa, deg, N);
    k_hist<<<(E + 255) / 256, 256, 0, stream>>>(dst, deg, E);
    k_scan1<<<nb, 256, 0, stream>>>(deg, blksum, N);
    k_scan2<<<1, 256, 0, stream>>>(blksum, blkoff, nb);
    k_scan3<<<nb, 256, 0, stream>>>(deg, blkoff, rowptr, cursor, N, E);
    k_scatter<<<(E + 255) / 256, 256, 0, stream>>>(src, dst, cursor, csr_src, E);
    k_att<<<N / 32, 256, 0, stream>>>(x, wa, asrc, adst);
    k_gat<<<(N * 64 + 255) / 256, 256, 0, stream>>>(rowptr, csr_src, asrc, adst,
                                                    x, z, N);
    k_zw<<<2000, 256, 0, stream>>>(z, W_gat, b_gat, gatT, N, n_node);
    k_p1<<<B * 16, 256, 0, stream>>>(gatT, Wt, b_ih1, b_hh1, P1, n_node, B);
    k_lstm<<<B, 256, 0, stream>>>(P1, wc2p, wi2p, w1p, b_ih2, b_hh2, h2finT, B, T);
    k_fin<<<B * 8, 256, 0, stream>>>(h2finT, W_lin, b_lin, (float*)d_out, n_node, B);
}